// Round 12
// baseline (71.347 us; speedup 1.0000x reference)
//
#include <hip/hip_runtime.h>

// GlobalAttention: out = softmax_j(scores) @ H
// scores[i,j] = sum_m lrelu(Wh1[i,m]+Wh2[j,m]) * a[m]
// lrelu(t) = 0.6t + 0.4|t|; row-constant part drops in softmax:
// scores'[i,j] = s2[j] + sum_m b[m]*|Wh1[i,m]+Wh2[j,m]|, b = 0.4a.
//
// R12 = R11 (R4C4 score @128thr, SMEM bglob, R8C8 PV) with the h[32] register
// spill removed: Hs staging is a 4-group x 8-f4 pipeline (<=64 VGPRs live).
// R11's 65MB WRITE_SIZE was scratch-spill traffic from holding 128 VGPRs of
// H across the softmax. LDS strides 68/260 fl (odd # of 16B quads).

#define HALF 524288

#define FENCE_BAR() do {                                   \
    __builtin_amdgcn_sched_barrier(0);                     \
    asm volatile("s_waitcnt lgkmcnt(0)" ::: "memory");     \
    __builtin_amdgcn_s_barrier();                          \
    __builtin_amdgcn_sched_barrier(0);                     \
} while (0)

__device__ __forceinline__ void f4fma(float4& acc, float s, float4 h) {
    acc.x = fmaf(s, h.x, acc.x);
    acc.y = fmaf(s, h.y, acc.y);
    acc.z = fmaf(s, h.z, acc.z);
    acc.w = fmaf(s, h.w, acc.w);
}

// ---------- K1: Whp[z][i][m] = sum_{k in half z} H[i][k]*Wre[m][k]
// (unchanged from R10 — proven)
__global__ __launch_bounds__(256) void k1_gemm_wh(const float* __restrict__ H,
                                                  const float* __restrict__ W,
                                                  float* __restrict__ Whp) {
    __shared__ float As[64][36];
    __shared__ float Bs[32][36];
    const int bi = blockIdx.x, bm = blockIdx.y, bz = blockIdx.z;
    const int t = threadIdx.x;
    const int ti = t >> 4, tj = t & 15;
    const int i0 = ti * 4;
    const int half = bm >> 3;
    const int kbase = bz * 128;
    float acc[4][2] = {};
    for (int kc = 0; kc < 128; kc += 32) {
        const int kg = kbase + kc;
        {
            const int r = t >> 2, c = (t & 3) * 8;
            *(float4*)&As[r][c] = *(const float4*)&H[(bi * 64 + r) * 256 + kg + c];
            *(float4*)&As[r][c + 4] =
                *(const float4*)&H[(bi * 64 + r) * 256 + kg + c + 4];
        }
        {
            const int r = t >> 3, c = (t & 7) * 4;
            const int wrow = (bm * 32 + r) & 255;
            *(float4*)&Bs[r][c] =
                *(const float4*)&W[wrow * 512 + half * 256 + kg + c];
        }
        __syncthreads();
#pragma unroll
        for (int k = 0; k < 32; k += 4) {
            float4 a[4], b[2];
#pragma unroll
            for (int r = 0; r < 4; ++r) a[r] = *(const float4*)&As[i0 + r][k];
#pragma unroll
            for (int c = 0; c < 2; ++c) b[c] = *(const float4*)&Bs[tj + 16 * c][k];
#pragma unroll
            for (int r = 0; r < 4; ++r)
#pragma unroll
                for (int c = 0; c < 2; ++c) {
                    acc[r][c] = fmaf(a[r].x, b[c].x, acc[r][c]);
                    acc[r][c] = fmaf(a[r].y, b[c].y, acc[r][c]);
                    acc[r][c] = fmaf(a[r].z, b[c].z, acc[r][c]);
                    acc[r][c] = fmaf(a[r].w, b[c].w, acc[r][c]);
                }
        }
        __syncthreads();
    }
    float* dst = Whp + (size_t)bz * HALF;
#pragma unroll
    for (int r = 0; r < 4; ++r)
#pragma unroll
        for (int c = 0; c < 2; ++c)
            dst[(size_t)(bi * 64 + i0 + r) * 512 + bm * 32 + tj + 16 * c] = acc[r][c];
}

// ---------- kW: Wh = Whp0+Whp1, s2[j] = 0.6*sum a[m]*Wh2[j][m], bglob = 0.4a.
__global__ __launch_bounds__(256) void kW_merge(const float* __restrict__ Whp,
                                                const float* __restrict__ a,
                                                float* __restrict__ Wh,
                                                float* __restrict__ s2,
                                                float* __restrict__ bglob) {
    const int t = threadIdx.x;
    const int row = blockIdx.x * 2 + (t >> 7);
    const int col = (t & 127) * 4;
    const size_t off = (size_t)row * 512 + col;
    float4 v0 = *(const float4*)&Whp[off];
    float4 v1 = *(const float4*)&Whp[HALF + off];
    float4 v = make_float4(v0.x + v1.x, v0.y + v1.y, v0.z + v1.z, v0.w + v1.w);
    *(float4*)&Wh[off] = v;
    if (col >= 256) {
        float4 av = *(const float4*)&a[col - 256];
        float p = av.x * v.x + av.y * v.y + av.z * v.z + av.w * v.w;
#pragma unroll
        for (int o = 32; o > 0; o >>= 1) p += __shfl_xor(p, o);
        if ((t & 63) == 0) s2[row] = 0.6f * p;
    }
    if (blockIdx.x == 0 && t < 64) {
        float4 av = *(const float4*)&a[t * 4];
        *(float4*)&bglob[t * 4] =
            make_float4(0.4f * av.x, 0.4f * av.y, 0.4f * av.z, 0.4f * av.w);
    }
}

// ---------- KF: flash block = 32 i x 64 j, 128 threads, R4C4 score, R8C8 PV.
// Grid (32,16) = 512 blocks -> 2 blocks/CU (73.5 KB LDS each).
__global__ __launch_bounds__(128) void kF_flash(const float* __restrict__ Wh,
                                                const float* __restrict__ bglob,
                                                const float* __restrict__ s2,
                                                const float* __restrict__ H,
                                                float* __restrict__ avp,
                                                float* __restrict__ mbuf,
                                                float* __restrict__ lbuf) {
    __shared__ float SH[16640];  // score: X1[2][32][68]+X2[2][64][68]; PV: Hs[64][260]
    __shared__ float P[2176];    // 32 x 68
    float* X1 = SH;
    float* X2 = SH + 4352;
    float* Hs = SH;
    const int bi = blockIdx.x, bj = blockIdx.y;
    const int t = threadIdx.x;
    const int ti = t >> 4, tj = t & 15;  // ti 0..7, tj 0..15
    const int i0 = ti * 4;
    // score staging: X1 32x64 (4 f4/thr), X2 64x64 (8 f4/thr)
    const int r1 = t >> 2, c1 = (t & 3) * 16;
    const int r2 = t >> 1, c2 = (t & 1) * 32;
    const float* g1 = Wh + (size_t)(bi * 32 + r1) * 512 + c1;
    const float* g2 = Wh + (size_t)(bj * 64 + r2) * 512 + 256 + c2;
    // PV H staging: 64x256, 32 f4/thr total (4 groups of 8)
    const int hr = t & 63, hcb = (t >> 6) * 128;
    const float* gH = H + (size_t)(bj * 64 + hr) * 256 + hcb;

    float4 A[12], B[12];

#define LOADC(R, mc) do {                                       \
    R[0] = *(const float4*)(g1 + (mc) * 64);                    \
    R[1] = *(const float4*)(g1 + (mc) * 64 + 4);                \
    R[2] = *(const float4*)(g1 + (mc) * 64 + 8);                \
    R[3] = *(const float4*)(g1 + (mc) * 64 + 12);               \
    R[4] = *(const float4*)(g2 + (mc) * 64);                    \
    R[5] = *(const float4*)(g2 + (mc) * 64 + 4);                \
    R[6] = *(const float4*)(g2 + (mc) * 64 + 8);                \
    R[7] = *(const float4*)(g2 + (mc) * 64 + 12);               \
    R[8] = *(const float4*)(g2 + (mc) * 64 + 16);               \
    R[9] = *(const float4*)(g2 + (mc) * 64 + 20);               \
    R[10] = *(const float4*)(g2 + (mc) * 64 + 24);              \
    R[11] = *(const float4*)(g2 + (mc) * 64 + 28); } while (0)
#define WRITEC(R, buf) do {                                     \
    *(float4*)&X1[((buf) * 32 + r1) * 68 + c1] = R[0];          \
    *(float4*)&X1[((buf) * 32 + r1) * 68 + c1 + 4] = R[1];      \
    *(float4*)&X1[((buf) * 32 + r1) * 68 + c1 + 8] = R[2];      \
    *(float4*)&X1[((buf) * 32 + r1) * 68 + c1 + 12] = R[3];     \
    *(float4*)&X2[((buf) * 64 + r2) * 68 + c2] = R[4];          \
    *(float4*)&X2[((buf) * 64 + r2) * 68 + c2 + 4] = R[5];      \
    *(float4*)&X2[((buf) * 64 + r2) * 68 + c2 + 8] = R[6];      \
    *(float4*)&X2[((buf) * 64 + r2) * 68 + c2 + 12] = R[7];     \
    *(float4*)&X2[((buf) * 64 + r2) * 68 + c2 + 16] = R[8];     \
    *(float4*)&X2[((buf) * 64 + r2) * 68 + c2 + 20] = R[9];     \
    *(float4*)&X2[((buf) * 64 + r2) * 68 + c2 + 24] = R[10];    \
    *(float4*)&X2[((buf) * 64 + r2) * 68 + c2 + 28] = R[11]; } while (0)

    // prologue
    LOADC(A, 0);
    LOADC(B, 1);
    float s2v0 = s2[bj * 64 + tj];
    float s2v1 = s2[bj * 64 + tj + 16];
    float s2v2 = s2[bj * 64 + tj + 32];
    float s2v3 = s2[bj * 64 + tj + 48];
    WRITEC(A, 0);   // waits only A's loads (counted vmcnt)
    FENCE_BAR();

    float acc[4][4] = {};
#pragma unroll
    for (int mc = 0; mc < 4; ++mc) {
        const int buf = mc & 1;
        if (mc == 0) { WRITEC(B, 1); LOADC(A, 2); }
        else if (mc == 1) { WRITEC(A, 0); LOADC(B, 3); }
        else if (mc == 2) { WRITEC(B, 1); }
#pragma unroll
        for (int k = 0; k < 64; k += 4) {
            float4 x1[4], x2[4];
#pragma unroll
            for (int r = 0; r < 4; ++r)
                x1[r] = *(const float4*)&X1[(buf * 32 + i0 + r) * 68 + k];
#pragma unroll
            for (int c = 0; c < 4; ++c)
                x2[c] = *(const float4*)&X2[(buf * 64 + tj + 16 * c) * 68 + k];
            const float4 bv = *(const float4*)(bglob + mc * 64 + k);  // SMEM
#pragma unroll
            for (int r = 0; r < 4; ++r)
#pragma unroll
                for (int c = 0; c < 4; ++c) {
                    acc[r][c] = fmaf(fabsf(x1[r].x + x2[c].x), bv.x, acc[r][c]);
                    acc[r][c] = fmaf(fabsf(x1[r].y + x2[c].y), bv.y, acc[r][c]);
                    acc[r][c] = fmaf(fabsf(x1[r].z + x2[c].z), bv.z, acc[r][c]);
                    acc[r][c] = fmaf(fabsf(x1[r].w + x2[c].w), bv.w, acc[r][c]);
                }
        }
        FENCE_BAR();
    }

    // add s2
#pragma unroll
    for (int r = 0; r < 4; ++r) {
        acc[r][0] += s2v0; acc[r][1] += s2v1;
        acc[r][2] += s2v2; acc[r][3] += s2v3;
    }

    // issue PV H group 0 ONLY (8 f4 = 32 VGPRs; no spill) under softmax
    float4 h0[8], h1[8];
#pragma unroll
    for (int q = 0; q < 8; ++q) h0[q] = *(const float4*)(gH + q * 4);

    // local softmax over the 64-j chunk (reduce across 16 tj lanes)
    float mmv[4], llv[4];
#pragma unroll
    for (int r = 0; r < 4; ++r) {
        float mm = fmaxf(fmaxf(acc[r][0], acc[r][1]), fmaxf(acc[r][2], acc[r][3]));
        mm = fmaxf(mm, __shfl_xor(mm, 1));
        mm = fmaxf(mm, __shfl_xor(mm, 2));
        mm = fmaxf(mm, __shfl_xor(mm, 4));
        mm = fmaxf(mm, __shfl_xor(mm, 8));
        float l0 = 0.f;
#pragma unroll
        for (int c = 0; c < 4; ++c) {
            acc[r][c] = __expf(acc[r][c] - mm);
            l0 += acc[r][c];
        }
        l0 += __shfl_xor(l0, 1);
        l0 += __shfl_xor(l0, 2);
        l0 += __shfl_xor(l0, 4);
        l0 += __shfl_xor(l0, 8);
#pragma unroll
        for (int c = 0; c < 4; ++c) P[(i0 + r) * 68 + tj + 16 * c] = acc[r][c];
        mmv[r] = mm; llv[r] = l0;
    }
    FENCE_BAR();  // P visible; score region (SH) dead -> reusable as Hs

    // pipelined 4-group Hs staging (issue next group's loads, write current)
#pragma unroll
    for (int q = 0; q < 8; ++q) h1[q] = *(const float4*)(gH + 32 + q * 4);
#pragma unroll
    for (int q = 0; q < 8; ++q) *(float4*)&Hs[hr * 260 + hcb + q * 4] = h0[q];
#pragma unroll
    for (int q = 0; q < 8; ++q) h0[q] = *(const float4*)(gH + 64 + q * 4);
#pragma unroll
    for (int q = 0; q < 8; ++q) *(float4*)&Hs[hr * 260 + hcb + 32 + q * 4] = h1[q];
#pragma unroll
    for (int q = 0; q < 8; ++q) h1[q] = *(const float4*)(gH + 96 + q * 4);
#pragma unroll
    for (int q = 0; q < 8; ++q) *(float4*)&Hs[hr * 260 + hcb + 64 + q * 4] = h0[q];
#pragma unroll
    for (int q = 0; q < 8; ++q) *(float4*)&Hs[hr * 260 + hcb + 96 + q * 4] = h1[q];
    FENCE_BAR();  // Hs visible

    // PV: jj-outer, R8 x C8 (ca, cb), P reads broadcast.
    const int ti2 = t >> 5, tj2 = t & 31;
    const int ip = ti2 * 8;
    const int ca = tj2 * 4, cb = 128 + tj2 * 4;
    float4 acc2[8][2] = {};
#pragma unroll
    for (int jj = 0; jj < 64; jj += 4) {
        float4 pv[8];
#pragma unroll
        for (int r = 0; r < 8; ++r) pv[r] = *(const float4*)&P[(ip + r) * 68 + jj];
#pragma unroll
        for (int q = 0; q < 4; ++q) {
            float4 ha = *(const float4*)&Hs[(jj + q) * 260 + ca];
            float4 hb = *(const float4*)&Hs[(jj + q) * 260 + cb];
#pragma unroll
            for (int r = 0; r < 8; ++r) {
                const float s = (q == 0) ? pv[r].x : (q == 1) ? pv[r].y
                              : (q == 2) ? pv[r].z : pv[r].w;
                f4fma(acc2[r][0], s, ha);
                f4fma(acc2[r][1], s, hb);
            }
        }
    }
#pragma unroll
    for (int r = 0; r < 8; ++r) {
        const size_t o = (size_t)bj * 262144 + (size_t)(bi * 32 + ip + r) * 256;
        *(float4*)&avp[o + ca] = acc2[r][0];
        *(float4*)&avp[o + cb] = acc2[r][1];
    }
    if (tj == 0) {
        const int gi = bi * 32 + i0;
#pragma unroll
        for (int r = 0; r < 4; ++r) {
            mbuf[bj * 1024 + gi + r] = mmv[r];
            lbuf[bj * 1024 + gi + r] = llv[r];
        }
    }
#undef LOADC
#undef WRITEC
}

// ---------- KM: merge 16 j-chunks with flash rescaling.
__global__ __launch_bounds__(256) void kM_merge(const float* __restrict__ avp,
                                                const float* __restrict__ mbuf,
                                                const float* __restrict__ lbuf,
                                                float* __restrict__ out) {
    const int t = threadIdx.x;
    const int i = blockIdx.x * 4 + (t >> 6);
    const int c0 = (t & 63) * 4;
    float ms[16], es[16];
    float M = -1e30f;
#pragma unroll
    for (int s = 0; s < 16; ++s) {
        ms[s] = mbuf[s * 1024 + i];
        M = fmaxf(M, ms[s]);
    }
    float L = 0.f;
#pragma unroll
    for (int s = 0; s < 16; ++s) {
        es[s] = __expf(ms[s] - M);
        L = fmaf(es[s], lbuf[s * 1024 + i], L);
    }
    const float inv = 1.0f / L;
    float4 o = make_float4(0.f, 0.f, 0.f, 0.f);
#pragma unroll
    for (int s = 0; s < 16; ++s) {
        float4 p = *(const float4*)&avp[(size_t)s * 262144 + (size_t)i * 256 + c0];
        o.x = fmaf(es[s], p.x, o.x);
        o.y = fmaf(es[s], p.y, o.y);
        o.z = fmaf(es[s], p.z, o.z);
        o.w = fmaf(es[s], p.w, o.w);
    }
    o.x *= inv; o.y *= inv; o.z *= inv; o.w *= inv;
    *(float4*)&out[(size_t)i * 256 + c0] = o;
}

extern "C" void kernel_launch(void* const* d_in, const int* in_sizes, int n_in,
                              void* d_out, int out_size, void* d_ws, size_t ws_size,
                              hipStream_t stream) {
    const float* H = (const float*)d_in[0];
    const float* W = (const float*)d_in[1];
    const float* a = (const float*)d_in[2];
    float* out = (float*)d_out;
    float* ws = (float*)d_ws;

    // avp (4M floats) aliases Whp (1M floats): Whp dead after kW_merge.
    float* avp = ws;                     // 16 MB
    float* Whp = ws;                     // 4 MB (k1 out, kW in)
    float* Wh = ws + (4u << 20);         // 2 MB merged
    float* mbuf = Wh + HALF;             // 16K floats
    float* lbuf = mbuf + 16384;          // 16K floats
    float* s2 = lbuf + 16384;            // 1K floats
    float* bglob = s2 + 1024;            // 256 floats

    hipLaunchKernelGGL(k1_gemm_wh, dim3(16, 16, 2), dim3(256), 0, stream, H, W, Whp);
    hipLaunchKernelGGL(kW_merge, dim3(512), dim3(256), 0, stream, Whp, a, Wh, s2, bglob);
    hipLaunchKernelGGL(kF_flash, dim3(32, 16), dim3(128), 0, stream, Wh, bglob, s2, H,
                       avp, mbuf, lbuf);
    hipLaunchKernelGGL(kM_merge, dim3(256), dim3(256), 0, stream, avp, mbuf, lbuf, out);
}

// Round 13
// 70.094 us; speedup vs baseline: 1.0179x; 1.0179x over previous
//
#include <hip/hip_runtime.h>

// GlobalAttention: out = softmax_j(scores) @ H
// scores[i,j] = sum_m lrelu(Wh1[i,m]+Wh2[j,m]) * a[m]
// lrelu(t) = 0.6t + 0.4|t|; row-constant part drops in softmax:
// scores'[i,j] = s2[j] + sum_m b[m]*|Wh1[i,m]+Wh2[j,m]|, b = 0.4a.
//
// R13 = R12 with the score-staging register spill removed: SINGLE 12-f4
// staging set (was A[12]+B[12] = 96 VGPRs -> scratch, 48MB WRITE_SIZE).
// Loop: LOADC(mc+1) -> compute(mc) -> WRITEC(buf^1) -> FENCE (1 fence/chunk;
// counted vmcnt resolves during compute). LDS strides 68/260 (odd 16B quads).

#define HALF 524288

#define FENCE_BAR() do {                                   \
    __builtin_amdgcn_sched_barrier(0);                     \
    asm volatile("s_waitcnt lgkmcnt(0)" ::: "memory");     \
    __builtin_amdgcn_s_barrier();                          \
    __builtin_amdgcn_sched_barrier(0);                     \
} while (0)

__device__ __forceinline__ void f4fma(float4& acc, float s, float4 h) {
    acc.x = fmaf(s, h.x, acc.x);
    acc.y = fmaf(s, h.y, acc.y);
    acc.z = fmaf(s, h.z, acc.z);
    acc.w = fmaf(s, h.w, acc.w);
}

// ---------- K1: Whp[z][i][m] = sum_{k in half z} H[i][k]*Wre[m][k]
// (unchanged from R10 — proven)
__global__ __launch_bounds__(256) void k1_gemm_wh(const float* __restrict__ H,
                                                  const float* __restrict__ W,
                                                  float* __restrict__ Whp) {
    __shared__ float As[64][36];
    __shared__ float Bs[32][36];
    const int bi = blockIdx.x, bm = blockIdx.y, bz = blockIdx.z;
    const int t = threadIdx.x;
    const int ti = t >> 4, tj = t & 15;
    const int i0 = ti * 4;
    const int half = bm >> 3;
    const int kbase = bz * 128;
    float acc[4][2] = {};
    for (int kc = 0; kc < 128; kc += 32) {
        const int kg = kbase + kc;
        {
            const int r = t >> 2, c = (t & 3) * 8;
            *(float4*)&As[r][c] = *(const float4*)&H[(bi * 64 + r) * 256 + kg + c];
            *(float4*)&As[r][c + 4] =
                *(const float4*)&H[(bi * 64 + r) * 256 + kg + c + 4];
        }
        {
            const int r = t >> 3, c = (t & 7) * 4;
            const int wrow = (bm * 32 + r) & 255;
            *(float4*)&Bs[r][c] =
                *(const float4*)&W[wrow * 512 + half * 256 + kg + c];
        }
        __syncthreads();
#pragma unroll
        for (int k = 0; k < 32; k += 4) {
            float4 a[4], b[2];
#pragma unroll
            for (int r = 0; r < 4; ++r) a[r] = *(const float4*)&As[i0 + r][k];
#pragma unroll
            for (int c = 0; c < 2; ++c) b[c] = *(const float4*)&Bs[tj + 16 * c][k];
#pragma unroll
            for (int r = 0; r < 4; ++r)
#pragma unroll
                for (int c = 0; c < 2; ++c) {
                    acc[r][c] = fmaf(a[r].x, b[c].x, acc[r][c]);
                    acc[r][c] = fmaf(a[r].y, b[c].y, acc[r][c]);
                    acc[r][c] = fmaf(a[r].z, b[c].z, acc[r][c]);
                    acc[r][c] = fmaf(a[r].w, b[c].w, acc[r][c]);
                }
        }
        __syncthreads();
    }
    float* dst = Whp + (size_t)bz * HALF;
#pragma unroll
    for (int r = 0; r < 4; ++r)
#pragma unroll
        for (int c = 0; c < 2; ++c)
            dst[(size_t)(bi * 64 + i0 + r) * 512 + bm * 32 + tj + 16 * c] = acc[r][c];
}

// ---------- kW: Wh = Whp0+Whp1, s2[j] = 0.6*sum a[m]*Wh2[j][m], bglob = 0.4a.
__global__ __launch_bounds__(256) void kW_merge(const float* __restrict__ Whp,
                                                const float* __restrict__ a,
                                                float* __restrict__ Wh,
                                                float* __restrict__ s2,
                                                float* __restrict__ bglob) {
    const int t = threadIdx.x;
    const int row = blockIdx.x * 2 + (t >> 7);
    const int col = (t & 127) * 4;
    const size_t off = (size_t)row * 512 + col;
    float4 v0 = *(const float4*)&Whp[off];
    float4 v1 = *(const float4*)&Whp[HALF + off];
    float4 v = make_float4(v0.x + v1.x, v0.y + v1.y, v0.z + v1.z, v0.w + v1.w);
    *(float4*)&Wh[off] = v;
    if (col >= 256) {
        float4 av = *(const float4*)&a[col - 256];
        float p = av.x * v.x + av.y * v.y + av.z * v.z + av.w * v.w;
#pragma unroll
        for (int o = 32; o > 0; o >>= 1) p += __shfl_xor(p, o);
        if ((t & 63) == 0) s2[row] = 0.6f * p;
    }
    if (blockIdx.x == 0 && t < 64) {
        float4 av = *(const float4*)&a[t * 4];
        *(float4*)&bglob[t * 4] =
            make_float4(0.4f * av.x, 0.4f * av.y, 0.4f * av.z, 0.4f * av.w);
    }
}

// ---------- KF: flash block = 32 i x 64 j, 128 threads, R4C4 score, R8C8 PV.
// Grid (32,16) = 512 blocks -> 2 blocks/CU (75 KB LDS each).
__global__ __launch_bounds__(128) void kF_flash(const float* __restrict__ Wh,
                                                const float* __restrict__ bglob,
                                                const float* __restrict__ s2,
                                                const float* __restrict__ H,
                                                float* __restrict__ avp,
                                                float* __restrict__ mbuf,
                                                float* __restrict__ lbuf) {
    __shared__ float SH[16640];  // score: X1[2][32][68]+X2[2][64][68]; PV: Hs[64][260]
    __shared__ float P[2176];    // 32 x 68
    float* X1 = SH;
    float* X2 = SH + 4352;
    float* Hs = SH;
    const int bi = blockIdx.x, bj = blockIdx.y;
    const int t = threadIdx.x;
    const int ti = t >> 4, tj = t & 15;  // ti 0..7, tj 0..15
    const int i0 = ti * 4;
    // score staging: X1 32x64 (4 f4/thr), X2 64x64 (8 f4/thr)
    const int r1 = t >> 2, c1 = (t & 3) * 16;
    const int r2 = t >> 1, c2 = (t & 1) * 32;
    const float* g1 = Wh + (size_t)(bi * 32 + r1) * 512 + c1;
    const float* g2 = Wh + (size_t)(bj * 64 + r2) * 512 + 256 + c2;
    // PV H staging: 64x256, 32 f4/thr total (4 groups of 8)
    const int hr = t & 63, hcb = (t >> 6) * 128;
    const float* gH = H + (size_t)(bj * 64 + hr) * 256 + hcb;

    float4 A[12];  // SINGLE staging set (48 VGPRs) — no spill

#define LOADC(mc) do {                                          \
    A[0] = *(const float4*)(g1 + (mc) * 64);                    \
    A[1] = *(const float4*)(g1 + (mc) * 64 + 4);                \
    A[2] = *(const float4*)(g1 + (mc) * 64 + 8);                \
    A[3] = *(const float4*)(g1 + (mc) * 64 + 12);               \
    A[4] = *(const float4*)(g2 + (mc) * 64);                    \
    A[5] = *(const float4*)(g2 + (mc) * 64 + 4);                \
    A[6] = *(const float4*)(g2 + (mc) * 64 + 8);                \
    A[7] = *(const float4*)(g2 + (mc) * 64 + 12);               \
    A[8] = *(const float4*)(g2 + (mc) * 64 + 16);               \
    A[9] = *(const float4*)(g2 + (mc) * 64 + 20);               \
    A[10] = *(const float4*)(g2 + (mc) * 64 + 24);              \
    A[11] = *(const float4*)(g2 + (mc) * 64 + 28); } while (0)
#define WRITEC(buf) do {                                        \
    *(float4*)&X1[((buf) * 32 + r1) * 68 + c1] = A[0];          \
    *(float4*)&X1[((buf) * 32 + r1) * 68 + c1 + 4] = A[1];      \
    *(float4*)&X1[((buf) * 32 + r1) * 68 + c1 + 8] = A[2];      \
    *(float4*)&X1[((buf) * 32 + r1) * 68 + c1 + 12] = A[3];     \
    *(float4*)&X2[((buf) * 64 + r2) * 68 + c2] = A[4];          \
    *(float4*)&X2[((buf) * 64 + r2) * 68 + c2 + 4] = A[5];      \
    *(float4*)&X2[((buf) * 64 + r2) * 68 + c2 + 8] = A[6];      \
    *(float4*)&X2[((buf) * 64 + r2) * 68 + c2 + 12] = A[7];     \
    *(float4*)&X2[((buf) * 64 + r2) * 68 + c2 + 16] = A[8];     \
    *(float4*)&X2[((buf) * 64 + r2) * 68 + c2 + 20] = A[9];     \
    *(float4*)&X2[((buf) * 64 + r2) * 68 + c2 + 24] = A[10];    \
    *(float4*)&X2[((buf) * 64 + r2) * 68 + c2 + 28] = A[11]; } while (0)

    // prologue: stage chunk 0
    LOADC(0);
    float s2v0 = s2[bj * 64 + tj];
    float s2v1 = s2[bj * 64 + tj + 16];
    float s2v2 = s2[bj * 64 + tj + 32];
    float s2v3 = s2[bj * 64 + tj + 48];
    WRITEC(0);
    FENCE_BAR();

    float acc[4][4] = {};
#pragma unroll
    for (int mc = 0; mc < 4; ++mc) {
        const int buf = mc & 1;
        if (mc < 3) LOADC(mc + 1);  // issue; vmcnt waited at WRITEC below
#pragma unroll
        for (int k = 0; k < 64; k += 4) {
            float4 x1[4], x2[4];
#pragma unroll
            for (int r = 0; r < 4; ++r)
                x1[r] = *(const float4*)&X1[(buf * 32 + i0 + r) * 68 + k];
#pragma unroll
            for (int c = 0; c < 4; ++c)
                x2[c] = *(const float4*)&X2[(buf * 64 + tj + 16 * c) * 68 + k];
            const float4 bv = *(const float4*)(bglob + mc * 64 + k);  // SMEM
#pragma unroll
            for (int r = 0; r < 4; ++r)
#pragma unroll
                for (int c = 0; c < 4; ++c) {
                    acc[r][c] = fmaf(fabsf(x1[r].x + x2[c].x), bv.x, acc[r][c]);
                    acc[r][c] = fmaf(fabsf(x1[r].y + x2[c].y), bv.y, acc[r][c]);
                    acc[r][c] = fmaf(fabsf(x1[r].z + x2[c].z), bv.z, acc[r][c]);
                    acc[r][c] = fmaf(fabsf(x1[r].w + x2[c].w), bv.w, acc[r][c]);
                }
        }
        if (mc < 3) {
            // buf^1's last readers passed the fence at end of iter mc-1 -> safe
            WRITEC(buf ^ 1);
            FENCE_BAR();
        }
    }

    // add s2
#pragma unroll
    for (int r = 0; r < 4; ++r) {
        acc[r][0] += s2v0; acc[r][1] += s2v1;
        acc[r][2] += s2v2; acc[r][3] += s2v3;
    }

    // issue PV H group 0 (8 f4 = 32 VGPRs) under softmax
    float4 h0[8], h1[8];
#pragma unroll
    for (int q = 0; q < 8; ++q) h0[q] = *(const float4*)(gH + q * 4);

    // local softmax over the 64-j chunk (reduce across 16 tj lanes)
    float mmv[4], llv[4];
#pragma unroll
    for (int r = 0; r < 4; ++r) {
        float mm = fmaxf(fmaxf(acc[r][0], acc[r][1]), fmaxf(acc[r][2], acc[r][3]));
        mm = fmaxf(mm, __shfl_xor(mm, 1));
        mm = fmaxf(mm, __shfl_xor(mm, 2));
        mm = fmaxf(mm, __shfl_xor(mm, 4));
        mm = fmaxf(mm, __shfl_xor(mm, 8));
        float l0 = 0.f;
#pragma unroll
        for (int c = 0; c < 4; ++c) {
            acc[r][c] = __expf(acc[r][c] - mm);
            l0 += acc[r][c];
        }
        l0 += __shfl_xor(l0, 1);
        l0 += __shfl_xor(l0, 2);
        l0 += __shfl_xor(l0, 4);
        l0 += __shfl_xor(l0, 8);
#pragma unroll
        for (int c = 0; c < 4; ++c) P[(i0 + r) * 68 + tj + 16 * c] = acc[r][c];
        mmv[r] = mm; llv[r] = l0;
    }
    FENCE_BAR();  // P visible; score region (SH) dead -> reusable as Hs

    // pipelined 4-group Hs staging (<=64 VGPRs live)
#pragma unroll
    for (int q = 0; q < 8; ++q) h1[q] = *(const float4*)(gH + 32 + q * 4);
#pragma unroll
    for (int q = 0; q < 8; ++q) *(float4*)&Hs[hr * 260 + hcb + q * 4] = h0[q];
#pragma unroll
    for (int q = 0; q < 8; ++q) h0[q] = *(const float4*)(gH + 64 + q * 4);
#pragma unroll
    for (int q = 0; q < 8; ++q) *(float4*)&Hs[hr * 260 + hcb + 32 + q * 4] = h1[q];
#pragma unroll
    for (int q = 0; q < 8; ++q) h1[q] = *(const float4*)(gH + 96 + q * 4);
#pragma unroll
    for (int q = 0; q < 8; ++q) *(float4*)&Hs[hr * 260 + hcb + 64 + q * 4] = h0[q];
#pragma unroll
    for (int q = 0; q < 8; ++q) *(float4*)&Hs[hr * 260 + hcb + 96 + q * 4] = h1[q];
    FENCE_BAR();  // Hs visible

    // PV: jj-outer, R8 x C8 (ca, cb), P reads broadcast.
    const int ti2 = t >> 5, tj2 = t & 31;
    const int ip = ti2 * 8;
    const int ca = tj2 * 4, cb = 128 + tj2 * 4;
    float4 acc2[8][2] = {};
#pragma unroll
    for (int jj = 0; jj < 64; jj += 4) {
        float4 pv[8];
#pragma unroll
        for (int r = 0; r < 8; ++r) pv[r] = *(const float4*)&P[(ip + r) * 68 + jj];
#pragma unroll
        for (int q = 0; q < 4; ++q) {
            float4 ha = *(const float4*)&Hs[(jj + q) * 260 + ca];
            float4 hb = *(const float4*)&Hs[(jj + q) * 260 + cb];
#pragma unroll
            for (int r = 0; r < 8; ++r) {
                const float s = (q == 0) ? pv[r].x : (q == 1) ? pv[r].y
                              : (q == 2) ? pv[r].z : pv[r].w;
                f4fma(acc2[r][0], s, ha);
                f4fma(acc2[r][1], s, hb);
            }
        }
    }
#pragma unroll
    for (int r = 0; r < 8; ++r) {
        const size_t o = (size_t)bj * 262144 + (size_t)(bi * 32 + ip + r) * 256;
        *(float4*)&avp[o + ca] = acc2[r][0];
        *(float4*)&avp[o + cb] = acc2[r][1];
    }
    if (tj == 0) {
        const int gi = bi * 32 + i0;
#pragma unroll
        for (int r = 0; r < 4; ++r) {
            mbuf[bj * 1024 + gi + r] = mmv[r];
            lbuf[bj * 1024 + gi + r] = llv[r];
        }
    }
#undef LOADC
#undef WRITEC
}

// ---------- KM: merge 16 j-chunks with flash rescaling.
__global__ __launch_bounds__(256) void kM_merge(const float* __restrict__ avp,
                                                const float* __restrict__ mbuf,
                                                const float* __restrict__ lbuf,
                                                float* __restrict__ out) {
    const int t = threadIdx.x;
    const int i = blockIdx.x * 4 + (t >> 6);
    const int c0 = (t & 63) * 4;
    float ms[16], es[16];
    float M = -1e30f;
#pragma unroll
    for (int s = 0; s < 16; ++s) {
        ms[s] = mbuf[s * 1024 + i];
        M = fmaxf(M, ms[s]);
    }
    float L = 0.f;
#pragma unroll
    for (int s = 0; s < 16; ++s) {
        es[s] = __expf(ms[s] - M);
        L = fmaf(es[s], lbuf[s * 1024 + i], L);
    }
    const float inv = 1.0f / L;
    float4 o = make_float4(0.f, 0.f, 0.f, 0.f);
#pragma unroll
    for (int s = 0; s < 16; ++s) {
        float4 p = *(const float4*)&avp[(size_t)s * 262144 + (size_t)i * 256 + c0];
        o.x = fmaf(es[s], p.x, o.x);
        o.y = fmaf(es[s], p.y, o.y);
        o.z = fmaf(es[s], p.z, o.z);
        o.w = fmaf(es[s], p.w, o.w);
    }
    o.x *= inv; o.y *= inv; o.z *= inv; o.w *= inv;
    *(float4*)&out[(size_t)i * 256 + c0] = o;
}

extern "C" void kernel_launch(void* const* d_in, const int* in_sizes, int n_in,
                              void* d_out, int out_size, void* d_ws, size_t ws_size,
                              hipStream_t stream) {
    const float* H = (const float*)d_in[0];
    const float* W = (const float*)d_in[1];
    const float* a = (const float*)d_in[2];
    float* out = (float*)d_out;
    float* ws = (float*)d_ws;

    // avp (4M floats) aliases Whp (1M floats): Whp dead after kW_merge.
    float* avp = ws;                     // 16 MB
    float* Whp = ws;                     // 4 MB (k1 out, kW in)
    float* Wh = ws + (4u << 20);         // 2 MB merged
    float* mbuf = Wh + HALF;             // 16K floats
    float* lbuf = mbuf + 16384;          // 16K floats
    float* s2 = lbuf + 16384;            // 1K floats
    float* bglob = s2 + 1024;            // 256 floats

    hipLaunchKernelGGL(k1_gemm_wh, dim3(16, 16, 2), dim3(256), 0, stream, H, W, Whp);
    hipLaunchKernelGGL(kW_merge, dim3(512), dim3(256), 0, stream, Whp, a, Wh, s2, bglob);
    hipLaunchKernelGGL(kF_flash, dim3(32, 16), dim3(128), 0, stream, Wh, bglob, s2, H,
                       avp, mbuf, lbuf);
    hipLaunchKernelGGL(kM_merge, dim3(256), dim3(256), 0, stream, avp, mbuf, lbuf, out);
}

// Round 14
// 62.900 us; speedup vs baseline: 1.1343x; 1.1144x over previous
//
#include <hip/hip_runtime.h>

// GlobalAttention: out = softmax_j(scores) @ H
// scores[i,j] = sum_m lrelu(Wh1[i,m]+Wh2[j,m]) * a[m]
// lrelu(t) = 0.6t + 0.4|t|; row-constant part drops in softmax:
// scores'[i,j] = s2[j] + sum_m b[m]*|Wh1[i,m]+Wh2[j,m]|, b = 0.4a.
//
// R14 = R10 (proven 49.3us; 256-thread kF, R2C4 score, full-c PV) + 2 deltas:
//  (1) bv from bglob via SMEM (wave-uniform s_load) -> 6 DS reads/quad, was 7
//  (2) single-fence score loop (5 barriers, was 8) — pattern validated in R13
// LDS strides 68/260 floats (odd # of 16B quads -> strided rows conflict-free).

#define HALF 524288

#define FENCE_BAR() do {                                   \
    __builtin_amdgcn_sched_barrier(0);                     \
    asm volatile("s_waitcnt lgkmcnt(0)" ::: "memory");     \
    __builtin_amdgcn_s_barrier();                          \
    __builtin_amdgcn_sched_barrier(0);                     \
} while (0)

// ---------- K1: Whp[z][i][m] = sum_{k in half z} H[i][k]*Wre[m][k]
// Wre[m][k] = W[m&255][(m>>8)*256+k]. 64i x 32m tiles, k-split 2.
// Grid (16,16,2) = 512 blocks.  (Identical to R10.)
__global__ __launch_bounds__(256) void k1_gemm_wh(const float* __restrict__ H,
                                                  const float* __restrict__ W,
                                                  float* __restrict__ Whp) {
    __shared__ float As[64][36];
    __shared__ float Bs[32][36];
    const int bi = blockIdx.x, bm = blockIdx.y, bz = blockIdx.z;
    const int t = threadIdx.x;
    const int ti = t >> 4, tj = t & 15;
    const int i0 = ti * 4;
    const int half = bm >> 3;
    const int kbase = bz * 128;
    float acc[4][2] = {};
    for (int kc = 0; kc < 128; kc += 32) {
        const int kg = kbase + kc;
        {
            const int r = t >> 2, c = (t & 3) * 8;
            *(float4*)&As[r][c] = *(const float4*)&H[(bi * 64 + r) * 256 + kg + c];
            *(float4*)&As[r][c + 4] =
                *(const float4*)&H[(bi * 64 + r) * 256 + kg + c + 4];
        }
        {
            const int r = t >> 3, c = (t & 7) * 4;
            const int wrow = (bm * 32 + r) & 255;
            *(float4*)&Bs[r][c] =
                *(const float4*)&W[wrow * 512 + half * 256 + kg + c];
        }
        __syncthreads();
#pragma unroll
        for (int k = 0; k < 32; k += 4) {
            float4 a[4], b[2];
#pragma unroll
            for (int r = 0; r < 4; ++r) a[r] = *(const float4*)&As[i0 + r][k];
#pragma unroll
            for (int c = 0; c < 2; ++c) b[c] = *(const float4*)&Bs[tj + 16 * c][k];
#pragma unroll
            for (int r = 0; r < 4; ++r)
#pragma unroll
                for (int c = 0; c < 2; ++c) {
                    acc[r][c] = fmaf(a[r].x, b[c].x, acc[r][c]);
                    acc[r][c] = fmaf(a[r].y, b[c].y, acc[r][c]);
                    acc[r][c] = fmaf(a[r].z, b[c].z, acc[r][c]);
                    acc[r][c] = fmaf(a[r].w, b[c].w, acc[r][c]);
                }
        }
        __syncthreads();
    }
    float* dst = Whp + (size_t)bz * HALF;
#pragma unroll
    for (int r = 0; r < 4; ++r)
#pragma unroll
        for (int c = 0; c < 2; ++c)
            dst[(size_t)(bi * 64 + i0 + r) * 512 + bm * 32 + tj + 16 * c] = acc[r][c];
}

// ---------- kW: Wh = Whp0+Whp1, s2[j] = 0.6*sum a[m]*Wh2[j][m], bglob = 0.4a.
__global__ __launch_bounds__(256) void kW_merge(const float* __restrict__ Whp,
                                                const float* __restrict__ a,
                                                float* __restrict__ Wh,
                                                float* __restrict__ s2,
                                                float* __restrict__ bglob) {
    const int t = threadIdx.x;
    const int row = blockIdx.x * 2 + (t >> 7);
    const int col = (t & 127) * 4;
    const size_t off = (size_t)row * 512 + col;
    float4 v0 = *(const float4*)&Whp[off];
    float4 v1 = *(const float4*)&Whp[HALF + off];
    float4 v = make_float4(v0.x + v1.x, v0.y + v1.y, v0.z + v1.z, v0.w + v1.w);
    *(float4*)&Wh[off] = v;
    if (col >= 256) {
        float4 av = *(const float4*)&a[col - 256];
        float p = av.x * v.x + av.y * v.y + av.z * v.z + av.w * v.w;
#pragma unroll
        for (int o = 32; o > 0; o >>= 1) p += __shfl_xor(p, o);
        if ((t & 63) == 0) s2[row] = 0.6f * p;
    }
    if (blockIdx.x == 0 && t < 64) {
        float4 av = *(const float4*)&a[t * 4];
        *(float4*)&bglob[t * 4] =
            make_float4(0.4f * av.x, 0.4f * av.y, 0.4f * av.z, 0.4f * av.w);
    }
}

// ---------- KF: flash block = 32 i x 64 j, 256 threads. R2C4 score + full-c PV.
// Grid (32,16) = 512 blocks, 75 KB LDS -> 2 blocks/CU (8 waves).
__global__ __launch_bounds__(256) void kF_flash(const float* __restrict__ Wh,
                                                const float* __restrict__ bglob,
                                                const float* __restrict__ s2,
                                                const float* __restrict__ H,
                                                float* __restrict__ avp,
                                                float* __restrict__ mbuf,
                                                float* __restrict__ lbuf) {
    __shared__ float SH[16640];  // score: X1[2][32][68]+X2[2][64][68]; PV: Hs[64][260]
    __shared__ float P[32 * 68];
    float* X1 = SH;
    float* X2 = SH + 4352;
    float* Hs = SH;
    const int bi = blockIdx.x, bj = blockIdx.y;
    const int t = threadIdx.x;
    const int ti = t >> 4, tj = t & 15;
    const int i0 = ti * 2;
    const int r1 = t >> 3, c1 = (t & 7) * 8;   // X1 tile 32x64: 2 f4/thread
    const int r2 = t >> 2, c2 = (t & 3) * 16;  // X2 tile 64x64: 4 f4/thread
    const float* g1 = Wh + (size_t)(bi * 32 + r1) * 512 + c1;
    const float* g2 = Wh + (size_t)(bj * 64 + r2) * 512 + 256 + c2;
    const int hr = t >> 2, hc = (t & 3) * 64;  // Hs tile 64x256: 16 f4/thread
    const float* gH = H + (size_t)(bj * 64 + hr) * 256 + hc;

    float4 A0, A1, A2, A3, A4, A5;  // single 6-f4 staging set (24 VGPRs)

#define LOADC(mc) do { A0 = *(const float4*)(g1 + (mc)*64);   \
    A1 = *(const float4*)(g1 + (mc)*64 + 4);                  \
    A2 = *(const float4*)(g2 + (mc)*64);                      \
    A3 = *(const float4*)(g2 + (mc)*64 + 4);                  \
    A4 = *(const float4*)(g2 + (mc)*64 + 8);                  \
    A5 = *(const float4*)(g2 + (mc)*64 + 12); } while (0)
#define WRITEC(buf) do {                                      \
    *(float4*)&X1[((buf) * 32 + r1) * 68 + c1] = A0;          \
    *(float4*)&X1[((buf) * 32 + r1) * 68 + c1 + 4] = A1;      \
    *(float4*)&X2[((buf) * 64 + r2) * 68 + c2] = A2;          \
    *(float4*)&X2[((buf) * 64 + r2) * 68 + c2 + 4] = A3;      \
    *(float4*)&X2[((buf) * 64 + r2) * 68 + c2 + 8] = A4;      \
    *(float4*)&X2[((buf) * 64 + r2) * 68 + c2 + 12] = A5; } while (0)

    // prologue: stage chunk 0
    LOADC(0);
    float s2v0 = s2[bj * 64 + tj];
    float s2v1 = s2[bj * 64 + tj + 16];
    float s2v2 = s2[bj * 64 + tj + 32];
    float s2v3 = s2[bj * 64 + tj + 48];
    WRITEC(0);
    FENCE_BAR();

    float acc[2][4] = {};
#pragma unroll
    for (int mc = 0; mc < 4; ++mc) {
        const int buf = mc & 1;
        if (mc < 3) LOADC(mc + 1);  // in flight during compute (counted vmcnt)
#pragma unroll
        for (int k = 0; k < 64; k += 4) {
            float4 x1[2], x2[4];
#pragma unroll
            for (int r = 0; r < 2; ++r)
                x1[r] = *(const float4*)&X1[(buf * 32 + i0 + r) * 68 + k];
#pragma unroll
            for (int c = 0; c < 4; ++c)
                x2[c] = *(const float4*)&X2[(buf * 64 + tj + 16 * c) * 68 + k];
            const float4 bv = *(const float4*)(bglob + mc * 64 + k);  // SMEM
#pragma unroll
            for (int r = 0; r < 2; ++r)
#pragma unroll
                for (int c = 0; c < 4; ++c) {
                    acc[r][c] = fmaf(fabsf(x1[r].x + x2[c].x), bv.x, acc[r][c]);
                    acc[r][c] = fmaf(fabsf(x1[r].y + x2[c].y), bv.y, acc[r][c]);
                    acc[r][c] = fmaf(fabsf(x1[r].z + x2[c].z), bv.z, acc[r][c]);
                    acc[r][c] = fmaf(fabsf(x1[r].w + x2[c].w), bv.w, acc[r][c]);
                }
        }
        if (mc < 3) {
            // buf^1's readers passed the previous fence -> safe to overwrite
            WRITEC(buf ^ 1);
            FENCE_BAR();
        }
    }

    acc[0][0] += s2v0; acc[1][0] += s2v0;
    acc[0][1] += s2v1; acc[1][1] += s2v1;
    acc[0][2] += s2v2; acc[1][2] += s2v2;
    acc[0][3] += s2v3; acc[1][3] += s2v3;

    // issue PV H loads group 1 (cols hc..hc+31); latency hides under softmax
    float4 h0 = *(const float4*)(gH);
    float4 h1 = *(const float4*)(gH + 4);
    float4 h2 = *(const float4*)(gH + 8);
    float4 h3 = *(const float4*)(gH + 12);
    float4 h4 = *(const float4*)(gH + 16);
    float4 h5 = *(const float4*)(gH + 20);
    float4 h6 = *(const float4*)(gH + 24);
    float4 h7 = *(const float4*)(gH + 28);

    float mm0, mm1, l00, l01;
#pragma unroll
    for (int r = 0; r < 2; ++r) {
        float mm = fmaxf(fmaxf(acc[r][0], acc[r][1]), fmaxf(acc[r][2], acc[r][3]));
        mm = fmaxf(mm, __shfl_xor(mm, 1));
        mm = fmaxf(mm, __shfl_xor(mm, 2));
        mm = fmaxf(mm, __shfl_xor(mm, 4));
        mm = fmaxf(mm, __shfl_xor(mm, 8));
        float l0 = 0.f;
#pragma unroll
        for (int c = 0; c < 4; ++c) {
            acc[r][c] = __expf(acc[r][c] - mm);
            l0 += acc[r][c];
        }
        l0 += __shfl_xor(l0, 1);
        l0 += __shfl_xor(l0, 2);
        l0 += __shfl_xor(l0, 4);
        l0 += __shfl_xor(l0, 8);
#pragma unroll
        for (int c = 0; c < 4; ++c) P[(i0 + r) * 68 + tj + 16 * c] = acc[r][c];
        if (r == 0) { mm0 = mm; l00 = l0; } else { mm1 = mm; l01 = l0; }
    }
    FENCE_BAR();  // P visible; score region (SH) dead -> reusable as Hs

    *(float4*)&Hs[hr * 260 + hc] = h0;
    *(float4*)&Hs[hr * 260 + hc + 4] = h1;
    *(float4*)&Hs[hr * 260 + hc + 8] = h2;
    *(float4*)&Hs[hr * 260 + hc + 12] = h3;
    *(float4*)&Hs[hr * 260 + hc + 16] = h4;
    *(float4*)&Hs[hr * 260 + hc + 20] = h5;
    *(float4*)&Hs[hr * 260 + hc + 24] = h6;
    *(float4*)&Hs[hr * 260 + hc + 28] = h7;
    h0 = *(const float4*)(gH + 32);
    h1 = *(const float4*)(gH + 36);
    h2 = *(const float4*)(gH + 40);
    h3 = *(const float4*)(gH + 44);
    h4 = *(const float4*)(gH + 48);
    h5 = *(const float4*)(gH + 52);
    h6 = *(const float4*)(gH + 56);
    h7 = *(const float4*)(gH + 60);
    *(float4*)&Hs[hr * 260 + hc + 32] = h0;
    *(float4*)&Hs[hr * 260 + hc + 36] = h1;
    *(float4*)&Hs[hr * 260 + hc + 40] = h2;
    *(float4*)&Hs[hr * 260 + hc + 44] = h3;
    *(float4*)&Hs[hr * 260 + hc + 48] = h4;
    *(float4*)&Hs[hr * 260 + hc + 52] = h5;
    *(float4*)&Hs[hr * 260 + hc + 56] = h6;
    *(float4*)&Hs[hr * 260 + hc + 60] = h7;
    FENCE_BAR();  // Hs visible

    // PV: jj-outer, P read once, full c-range (c-pair ca/cb) per thread.
    const int ti2 = t >> 5, tj2 = t & 31;
    const int ip = ti2 * 4;
    const int ca = tj2 * 4, cb = 128 + tj2 * 4;
    float4 acc2[4][2] = {};
#pragma unroll
    for (int jj = 0; jj < 64; jj += 4) {
        float4 pv[4];
#pragma unroll
        for (int r = 0; r < 4; ++r) pv[r] = *(const float4*)&P[(ip + r) * 68 + jj];
#pragma unroll
        for (int q = 0; q < 4; ++q) {
            float4 ha = *(const float4*)&Hs[(jj + q) * 260 + ca];
            float4 hb = *(const float4*)&Hs[(jj + q) * 260 + cb];
#pragma unroll
            for (int r = 0; r < 4; ++r) {
                const float s = (q == 0) ? pv[r].x : (q == 1) ? pv[r].y
                              : (q == 2) ? pv[r].z : pv[r].w;
                acc2[r][0].x = fmaf(s, ha.x, acc2[r][0].x);
                acc2[r][0].y = fmaf(s, ha.y, acc2[r][0].y);
                acc2[r][0].z = fmaf(s, ha.z, acc2[r][0].z);
                acc2[r][0].w = fmaf(s, ha.w, acc2[r][0].w);
                acc2[r][1].x = fmaf(s, hb.x, acc2[r][1].x);
                acc2[r][1].y = fmaf(s, hb.y, acc2[r][1].y);
                acc2[r][1].z = fmaf(s, hb.z, acc2[r][1].z);
                acc2[r][1].w = fmaf(s, hb.w, acc2[r][1].w);
            }
        }
    }
#pragma unroll
    for (int r = 0; r < 4; ++r) {
        const size_t o = (size_t)bj * 262144 + (size_t)(bi * 32 + ip + r) * 256;
        *(float4*)&avp[o + ca] = acc2[r][0];
        *(float4*)&avp[o + cb] = acc2[r][1];
    }
    if (tj == 0) {
        const int gi = bi * 32 + i0;
        mbuf[bj * 1024 + gi] = mm0;
        lbuf[bj * 1024 + gi] = l00;
        mbuf[bj * 1024 + gi + 1] = mm1;
        lbuf[bj * 1024 + gi + 1] = l01;
    }
#undef LOADC
#undef WRITEC
}

// ---------- KM: merge 16 j-chunks with flash rescaling.
__global__ __launch_bounds__(256) void kM_merge(const float* __restrict__ avp,
                                                const float* __restrict__ mbuf,
                                                const float* __restrict__ lbuf,
                                                float* __restrict__ out) {
    const int t = threadIdx.x;
    const int i = blockIdx.x * 4 + (t >> 6);
    const int c0 = (t & 63) * 4;
    float ms[16], es[16];
    float M = -1e30f;
#pragma unroll
    for (int s = 0; s < 16; ++s) {
        ms[s] = mbuf[s * 1024 + i];
        M = fmaxf(M, ms[s]);
    }
    float L = 0.f;
#pragma unroll
    for (int s = 0; s < 16; ++s) {
        es[s] = __expf(ms[s] - M);
        L = fmaf(es[s], lbuf[s * 1024 + i], L);
    }
    const float inv = 1.0f / L;
    float4 o = make_float4(0.f, 0.f, 0.f, 0.f);
#pragma unroll
    for (int s = 0; s < 16; ++s) {
        float4 p = *(const float4*)&avp[(size_t)s * 262144 + (size_t)i * 256 + c0];
        o.x = fmaf(es[s], p.x, o.x);
        o.y = fmaf(es[s], p.y, o.y);
        o.z = fmaf(es[s], p.z, o.z);
        o.w = fmaf(es[s], p.w, o.w);
    }
    o.x *= inv; o.y *= inv; o.z *= inv; o.w *= inv;
    *(float4*)&out[(size_t)i * 256 + c0] = o;
}

extern "C" void kernel_launch(void* const* d_in, const int* in_sizes, int n_in,
                              void* d_out, int out_size, void* d_ws, size_t ws_size,
                              hipStream_t stream) {
    const float* H = (const float*)d_in[0];
    const float* W = (const float*)d_in[1];
    const float* a = (const float*)d_in[2];
    float* out = (float*)d_out;
    float* ws = (float*)d_ws;

    // avp (4M floats) aliases Whp (1M floats): Whp dead after kW_merge.
    float* avp = ws;                     // 16 MB
    float* Whp = ws;                     // 4 MB (k1 out, kW in)
    float* Wh = ws + (4u << 20);         // 2 MB merged
    float* mbuf = Wh + HALF;             // 16K floats
    float* lbuf = mbuf + 16384;          // 16K floats
    float* s2 = lbuf + 16384;            // 1K floats
    float* bglob = s2 + 1024;            // 256 floats

    hipLaunchKernelGGL(k1_gemm_wh, dim3(16, 16, 2), dim3(256), 0, stream, H, W, Whp);
    hipLaunchKernelGGL(kW_merge, dim3(512), dim3(256), 0, stream, Whp, a, Wh, s2, bglob);
    hipLaunchKernelGGL(kF_flash, dim3(32, 16), dim3(256), 0, stream, Wh, bglob, s2, H,
                       avp, mbuf, lbuf);
    hipLaunchKernelGGL(kM_merge, dim3(256), dim3(256), 0, stream, avp, mbuf, lbuf, out);
}

// Round 15
// 49.184 us; speedup vs baseline: 1.4506x; 1.2789x over previous
//
#include <hip/hip_runtime.h>

// GlobalAttention: out = softmax_j(scores) @ H
// scores[i,j] = sum_m lrelu(Wh1[i,m]+Wh2[j,m]) * a[m]
// lrelu(t) = 0.6t + 0.4|t|; row-constant part drops in softmax:
// scores'[i,j] = s2[j] + sum_m b[m]*|Wh1[i,m]+Wh2[j,m]|, b = 0.4a.
//
// R15 = R10 verbatim (proven 49.3us best). R11-R14 kF variants all regressed:
//  - 128-thr R4C4 arc: VGPR spill (R11/12: 65MB scratch WRITE) or VGPR=248
//    occupancy collapse (R13);
//  - single-fence + SMEM-bglob (R14): VGPR 180 + in-loop VMEM latency, +17us.
// Structure: k1 (k-split GEMM) -> kW (merge + s2) -> kF (flash: R2C4 score,
// 2-set dbuf staging, full-c jj-outer PV, Hs aliases score LDS) -> kM (merge).
// LDS strides 68/260 floats = odd # of 16B quads -> strided rows conflict-free.

#define HALF 524288

#define FENCE_BAR() do {                                   \
    __builtin_amdgcn_sched_barrier(0);                     \
    asm volatile("s_waitcnt lgkmcnt(0)" ::: "memory");     \
    __builtin_amdgcn_s_barrier();                          \
    __builtin_amdgcn_sched_barrier(0);                     \
} while (0)

// ---------- K1: Whp[z][i][m] = sum_{k in half z} H[i][k]*Wre[m][k]
// Wre[m][k] = W[m&255][(m>>8)*256+k]. 64i x 32m tiles, k-split 2.
// Grid (16,16,2) = 512 blocks.
__global__ __launch_bounds__(256) void k1_gemm_wh(const float* __restrict__ H,
                                                  const float* __restrict__ W,
                                                  float* __restrict__ Whp) {
    __shared__ float As[64][36];
    __shared__ float Bs[32][36];
    const int bi = blockIdx.x, bm = blockIdx.y, bz = blockIdx.z;
    const int t = threadIdx.x;
    const int ti = t >> 4, tj = t & 15;
    const int i0 = ti * 4;
    const int half = bm >> 3;
    const int kbase = bz * 128;
    float acc[4][2] = {};
    for (int kc = 0; kc < 128; kc += 32) {
        const int kg = kbase + kc;
        {
            const int r = t >> 2, c = (t & 3) * 8;
            *(float4*)&As[r][c] = *(const float4*)&H[(bi * 64 + r) * 256 + kg + c];
            *(float4*)&As[r][c + 4] =
                *(const float4*)&H[(bi * 64 + r) * 256 + kg + c + 4];
        }
        {
            const int r = t >> 3, c = (t & 7) * 4;
            const int wrow = (bm * 32 + r) & 255;
            *(float4*)&Bs[r][c] =
                *(const float4*)&W[wrow * 512 + half * 256 + kg + c];
        }
        __syncthreads();
#pragma unroll
        for (int k = 0; k < 32; k += 4) {
            float4 a[4], b[2];
#pragma unroll
            for (int r = 0; r < 4; ++r) a[r] = *(const float4*)&As[i0 + r][k];
#pragma unroll
            for (int c = 0; c < 2; ++c) b[c] = *(const float4*)&Bs[tj + 16 * c][k];
#pragma unroll
            for (int r = 0; r < 4; ++r)
#pragma unroll
                for (int c = 0; c < 2; ++c) {
                    acc[r][c] = fmaf(a[r].x, b[c].x, acc[r][c]);
                    acc[r][c] = fmaf(a[r].y, b[c].y, acc[r][c]);
                    acc[r][c] = fmaf(a[r].z, b[c].z, acc[r][c]);
                    acc[r][c] = fmaf(a[r].w, b[c].w, acc[r][c]);
                }
        }
        __syncthreads();
    }
    float* dst = Whp + (size_t)bz * HALF;
#pragma unroll
    for (int r = 0; r < 4; ++r)
#pragma unroll
        for (int c = 0; c < 2; ++c)
            dst[(size_t)(bi * 64 + i0 + r) * 512 + bm * 32 + tj + 16 * c] = acc[r][c];
}

// ---------- kW: Wh = Whp0 + Whp1 (merged), s2[j] = 0.6*sum a[m]*Wh2[j][m].
__global__ __launch_bounds__(256) void kW_merge(const float* __restrict__ Whp,
                                                const float* __restrict__ a,
                                                float* __restrict__ Wh,
                                                float* __restrict__ s2) {
    const int t = threadIdx.x;
    const int row = blockIdx.x * 2 + (t >> 7);
    const int col = (t & 127) * 4;
    const size_t off = (size_t)row * 512 + col;
    float4 v0 = *(const float4*)&Whp[off];
    float4 v1 = *(const float4*)&Whp[HALF + off];
    float4 v = make_float4(v0.x + v1.x, v0.y + v1.y, v0.z + v1.z, v0.w + v1.w);
    *(float4*)&Wh[off] = v;
    if (col >= 256) {
        float4 av = *(const float4*)&a[col - 256];
        float p = av.x * v.x + av.y * v.y + av.z * v.z + av.w * v.w;
#pragma unroll
        for (int o = 32; o > 0; o >>= 1) p += __shfl_xor(p, o);
        if ((t & 63) == 0) s2[row] = 0.6f * p;
    }
}

// ---------- KF: flash block = 32 i x 64 j. R2C4 score + full-c PV.
// Grid (32,16) = 512 blocks, 256 thr, 75 KB LDS -> 2 blocks/CU.
__global__ __launch_bounds__(256) void kF_flash(const float* __restrict__ Wh,
                                                const float* __restrict__ a,
                                                const float* __restrict__ s2,
                                                const float* __restrict__ H,
                                                float* __restrict__ avp,
                                                float* __restrict__ mbuf,
                                                float* __restrict__ lbuf) {
    __shared__ float SH[16640];  // score: X1[2][32][68]+X2[2][64][68]; PV: Hs[64][260]
    __shared__ float P[32 * 68];
    __shared__ float bsh[256];
    float* X1 = SH;
    float* X2 = SH + 4352;
    float* Hs = SH;
    const int bi = blockIdx.x, bj = blockIdx.y;
    const int t = threadIdx.x;
    const int ti = t >> 4, tj = t & 15;
    const int i0 = ti * 2;
    const int r1 = t >> 3, c1 = (t & 7) * 8;   // X1 tile 32x64: 2 f4/thread
    const int r2 = t >> 2, c2 = (t & 3) * 16;  // X2 tile 64x64: 4 f4/thread
    const float* g1 = Wh + (size_t)(bi * 32 + r1) * 512 + c1;
    const float* g2 = Wh + (size_t)(bj * 64 + r2) * 512 + 256 + c2;
    const int hr = t >> 2, hc = (t & 3) * 64;  // Hs tile 64x256: 16 f4/thread
    const float* gH = H + (size_t)(bj * 64 + hr) * 256 + hc;

    float4 A0, A1, A2, A3, A4, A5, B0, B1, B2, B3, B4, B5;

#define LOADC_A(mc) do { A0 = *(const float4*)(g1 + (mc)*64); \
    A1 = *(const float4*)(g1 + (mc)*64 + 4);                  \
    A2 = *(const float4*)(g2 + (mc)*64);                      \
    A3 = *(const float4*)(g2 + (mc)*64 + 4);                  \
    A4 = *(const float4*)(g2 + (mc)*64 + 8);                  \
    A5 = *(const float4*)(g2 + (mc)*64 + 12); } while (0)
#define LOADC_B(mc) do { B0 = *(const float4*)(g1 + (mc)*64); \
    B1 = *(const float4*)(g1 + (mc)*64 + 4);                  \
    B2 = *(const float4*)(g2 + (mc)*64);                      \
    B3 = *(const float4*)(g2 + (mc)*64 + 4);                  \
    B4 = *(const float4*)(g2 + (mc)*64 + 8);                  \
    B5 = *(const float4*)(g2 + (mc)*64 + 12); } while (0)
#define WRITEC_A(buf) do {                                    \
    *(float4*)&X1[((buf) * 32 + r1) * 68 + c1] = A0;          \
    *(float4*)&X1[((buf) * 32 + r1) * 68 + c1 + 4] = A1;      \
    *(float4*)&X2[((buf) * 64 + r2) * 68 + c2] = A2;          \
    *(float4*)&X2[((buf) * 64 + r2) * 68 + c2 + 4] = A3;      \
    *(float4*)&X2[((buf) * 64 + r2) * 68 + c2 + 8] = A4;      \
    *(float4*)&X2[((buf) * 64 + r2) * 68 + c2 + 12] = A5; } while (0)
#define WRITEC_B(buf) do {                                    \
    *(float4*)&X1[((buf) * 32 + r1) * 68 + c1] = B0;          \
    *(float4*)&X1[((buf) * 32 + r1) * 68 + c1 + 4] = B1;      \
    *(float4*)&X2[((buf) * 64 + r2) * 68 + c2] = B2;          \
    *(float4*)&X2[((buf) * 64 + r2) * 68 + c2 + 4] = B3;      \
    *(float4*)&X2[((buf) * 64 + r2) * 68 + c2 + 8] = B4;      \
    *(float4*)&X2[((buf) * 64 + r2) * 68 + c2 + 12] = B5; } while (0)

    LOADC_A(0);
    float s2v0 = s2[bj * 64 + tj];
    float s2v1 = s2[bj * 64 + tj + 16];
    float s2v2 = s2[bj * 64 + tj + 32];
    float s2v3 = s2[bj * 64 + tj + 48];
    if (t < 64) {
        float4 av = *(const float4*)&a[t * 4];
        *(float4*)&bsh[t * 4] =
            make_float4(0.4f * av.x, 0.4f * av.y, 0.4f * av.z, 0.4f * av.w);
    }

    float acc[2][4] = {};
#pragma unroll
    for (int mc = 0; mc < 4; ++mc) {
        const int buf = mc & 1;
        if (mc < 3) {
            if (buf == 0) LOADC_B(mc + 1); else LOADC_A(mc + 1);
        }
        if (buf == 0) WRITEC_A(0); else WRITEC_B(1);
        FENCE_BAR();
#pragma unroll
        for (int k = 0; k < 64; k += 4) {
            float4 x1[2], x2[4];
#pragma unroll
            for (int r = 0; r < 2; ++r)
                x1[r] = *(const float4*)&X1[(buf * 32 + i0 + r) * 68 + k];
#pragma unroll
            for (int c = 0; c < 4; ++c)
                x2[c] = *(const float4*)&X2[(buf * 64 + tj + 16 * c) * 68 + k];
            const float4 bv = *(const float4*)&bsh[mc * 64 + k];
#pragma unroll
            for (int r = 0; r < 2; ++r)
#pragma unroll
                for (int c = 0; c < 4; ++c) {
                    acc[r][c] = fmaf(fabsf(x1[r].x + x2[c].x), bv.x, acc[r][c]);
                    acc[r][c] = fmaf(fabsf(x1[r].y + x2[c].y), bv.y, acc[r][c]);
                    acc[r][c] = fmaf(fabsf(x1[r].z + x2[c].z), bv.z, acc[r][c]);
                    acc[r][c] = fmaf(fabsf(x1[r].w + x2[c].w), bv.w, acc[r][c]);
                }
        }
        FENCE_BAR();
    }

    acc[0][0] += s2v0; acc[1][0] += s2v0;
    acc[0][1] += s2v1; acc[1][1] += s2v1;
    acc[0][2] += s2v2; acc[1][2] += s2v2;
    acc[0][3] += s2v3; acc[1][3] += s2v3;

    // issue PV H loads group 1 (cols hc..hc+31); latency hides under softmax
    float4 h0 = *(const float4*)(gH);
    float4 h1 = *(const float4*)(gH + 4);
    float4 h2 = *(const float4*)(gH + 8);
    float4 h3 = *(const float4*)(gH + 12);
    float4 h4 = *(const float4*)(gH + 16);
    float4 h5 = *(const float4*)(gH + 20);
    float4 h6 = *(const float4*)(gH + 24);
    float4 h7 = *(const float4*)(gH + 28);

    float mm0, mm1, l00, l01;
#pragma unroll
    for (int r = 0; r < 2; ++r) {
        float mm = fmaxf(fmaxf(acc[r][0], acc[r][1]), fmaxf(acc[r][2], acc[r][3]));
        mm = fmaxf(mm, __shfl_xor(mm, 1));
        mm = fmaxf(mm, __shfl_xor(mm, 2));
        mm = fmaxf(mm, __shfl_xor(mm, 4));
        mm = fmaxf(mm, __shfl_xor(mm, 8));
        float l0 = 0.f;
#pragma unroll
        for (int c = 0; c < 4; ++c) {
            acc[r][c] = __expf(acc[r][c] - mm);
            l0 += acc[r][c];
        }
        l0 += __shfl_xor(l0, 1);
        l0 += __shfl_xor(l0, 2);
        l0 += __shfl_xor(l0, 4);
        l0 += __shfl_xor(l0, 8);
#pragma unroll
        for (int c = 0; c < 4; ++c) P[(i0 + r) * 68 + tj + 16 * c] = acc[r][c];
        if (r == 0) { mm0 = mm; l00 = l0; } else { mm1 = mm; l01 = l0; }
    }
    FENCE_BAR();  // P visible; score region (SH) dead -> reusable as Hs

    *(float4*)&Hs[hr * 260 + hc] = h0;
    *(float4*)&Hs[hr * 260 + hc + 4] = h1;
    *(float4*)&Hs[hr * 260 + hc + 8] = h2;
    *(float4*)&Hs[hr * 260 + hc + 12] = h3;
    *(float4*)&Hs[hr * 260 + hc + 16] = h4;
    *(float4*)&Hs[hr * 260 + hc + 20] = h5;
    *(float4*)&Hs[hr * 260 + hc + 24] = h6;
    *(float4*)&Hs[hr * 260 + hc + 28] = h7;
    h0 = *(const float4*)(gH + 32);
    h1 = *(const float4*)(gH + 36);
    h2 = *(const float4*)(gH + 40);
    h3 = *(const float4*)(gH + 44);
    h4 = *(const float4*)(gH + 48);
    h5 = *(const float4*)(gH + 52);
    h6 = *(const float4*)(gH + 56);
    h7 = *(const float4*)(gH + 60);
    *(float4*)&Hs[hr * 260 + hc + 32] = h0;
    *(float4*)&Hs[hr * 260 + hc + 36] = h1;
    *(float4*)&Hs[hr * 260 + hc + 40] = h2;
    *(float4*)&Hs[hr * 260 + hc + 44] = h3;
    *(float4*)&Hs[hr * 260 + hc + 48] = h4;
    *(float4*)&Hs[hr * 260 + hc + 52] = h5;
    *(float4*)&Hs[hr * 260 + hc + 56] = h6;
    *(float4*)&Hs[hr * 260 + hc + 60] = h7;
    FENCE_BAR();  // Hs visible

    // PV: jj-outer, P read once, full c-range (c-pair ca/cb) per thread.
    const int ti2 = t >> 5, tj2 = t & 31;
    const int ip = ti2 * 4;
    const int ca = tj2 * 4, cb = 128 + tj2 * 4;
    float4 acc2[4][2] = {};
#pragma unroll
    for (int jj = 0; jj < 64; jj += 4) {
        float4 pv[4];
#pragma unroll
        for (int r = 0; r < 4; ++r) pv[r] = *(const float4*)&P[(ip + r) * 68 + jj];
#pragma unroll
        for (int q = 0; q < 4; ++q) {
            float4 ha = *(const float4*)&Hs[(jj + q) * 260 + ca];
            float4 hb = *(const float4*)&Hs[(jj + q) * 260 + cb];
#pragma unroll
            for (int r = 0; r < 4; ++r) {
                const float s = (q == 0) ? pv[r].x : (q == 1) ? pv[r].y
                              : (q == 2) ? pv[r].z : pv[r].w;
                acc2[r][0].x = fmaf(s, ha.x, acc2[r][0].x);
                acc2[r][0].y = fmaf(s, ha.y, acc2[r][0].y);
                acc2[r][0].z = fmaf(s, ha.z, acc2[r][0].z);
                acc2[r][0].w = fmaf(s, ha.w, acc2[r][0].w);
                acc2[r][1].x = fmaf(s, hb.x, acc2[r][1].x);
                acc2[r][1].y = fmaf(s, hb.y, acc2[r][1].y);
                acc2[r][1].z = fmaf(s, hb.z, acc2[r][1].z);
                acc2[r][1].w = fmaf(s, hb.w, acc2[r][1].w);
            }
        }
    }
#pragma unroll
    for (int r = 0; r < 4; ++r) {
        const size_t o = (size_t)bj * 262144 + (size_t)(bi * 32 + ip + r) * 256;
        *(float4*)&avp[o + ca] = acc2[r][0];
        *(float4*)&avp[o + cb] = acc2[r][1];
    }
    if (tj == 0) {
        const int gi = bi * 32 + i0;
        mbuf[bj * 1024 + gi] = mm0;
        lbuf[bj * 1024 + gi] = l00;
        mbuf[bj * 1024 + gi + 1] = mm1;
        lbuf[bj * 1024 + gi + 1] = l01;
    }
#undef LOADC_A
#undef LOADC_B
#undef WRITEC_A
#undef WRITEC_B
}

// ---------- KM: merge 16 j-chunks with flash rescaling.
__global__ __launch_bounds__(256) void kM_merge(const float* __restrict__ avp,
                                                const float* __restrict__ mbuf,
                                                const float* __restrict__ lbuf,
                                                float* __restrict__ out) {
    const int t = threadIdx.x;
    const int i = blockIdx.x * 4 + (t >> 6);
    const int c0 = (t & 63) * 4;
    float ms[16], es[16];
    float M = -1e30f;
#pragma unroll
    for (int s = 0; s < 16; ++s) {
        ms[s] = mbuf[s * 1024 + i];
        M = fmaxf(M, ms[s]);
    }
    float L = 0.f;
#pragma unroll
    for (int s = 0; s < 16; ++s) {
        es[s] = __expf(ms[s] - M);
        L = fmaf(es[s], lbuf[s * 1024 + i], L);
    }
    const float inv = 1.0f / L;
    float4 o = make_float4(0.f, 0.f, 0.f, 0.f);
#pragma unroll
    for (int s = 0; s < 16; ++s) {
        float4 p = *(const float4*)&avp[(size_t)s * 262144 + (size_t)i * 256 + c0];
        o.x = fmaf(es[s], p.x, o.x);
        o.y = fmaf(es[s], p.y, o.y);
        o.z = fmaf(es[s], p.z, o.z);
        o.w = fmaf(es[s], p.w, o.w);
    }
    o.x *= inv; o.y *= inv; o.z *= inv; o.w *= inv;
    *(float4*)&out[(size_t)i * 256 + c0] = o;
}

extern "C" void kernel_launch(void* const* d_in, const int* in_sizes, int n_in,
                              void* d_out, int out_size, void* d_ws, size_t ws_size,
                              hipStream_t stream) {
    const float* H = (const float*)d_in[0];
    const float* W = (const float*)d_in[1];
    const float* a = (const float*)d_in[2];
    float* out = (float*)d_out;
    float* ws = (float*)d_ws;

    // avp (16 x 262144 floats) aliases Whp (2 x 524288 floats): Whp dead
    // after kW_merge, before kF writes avp.
    float* avp = ws;                     // 16 MB
    float* Whp = ws;                     // 4 MB (k1 out, kW in)
    float* Wh = ws + (4u << 20);         // 2 MB merged
    float* mbuf = Wh + HALF;             // 16K floats
    float* lbuf = mbuf + 16384;          // 16K floats
    float* s2 = lbuf + 16384;            // 1K floats

    hipLaunchKernelGGL(k1_gemm_wh, dim3(16, 16, 2), dim3(256), 0, stream, H, W, Whp);
    hipLaunchKernelGGL(kW_merge, dim3(512), dim3(256), 0, stream, Whp, a, Wh, s2);
    hipLaunchKernelGGL(kF_flash, dim3(32, 16), dim3(256), 0, stream, Wh, a, s2, H,
                       avp, mbuf, lbuf);
    hipLaunchKernelGGL(kM_merge, dim3(256), dim3(256), 0, stream, avp, mbuf, lbuf, out);
}